// Round 1
// baseline (8772.544 us; speedup 1.0000x reference)
//
#include <hip/hip_runtime.h>

#define NSTEP 2048

typedef __attribute__((ext_vector_type(8))) short short8;
typedef __attribute__((ext_vector_type(4))) float f32x4;

static __device__ __forceinline__ unsigned short f2bf(float f){
  unsigned u = __builtin_bit_cast(unsigned, f);
  u += 0x7FFFu + ((u >> 16) & 1u);   // RNE
  return (unsigned short)(u >> 16);
}

// ---------------- fp32 -> bf16 (for W_ih) ----------------
__global__ __launch_bounds__(256,1)
void cvt_bf16_k(const float* __restrict__ in, unsigned short* __restrict__ out, int n4){
  int i = blockIdx.x*256 + threadIdx.x;
  if (i < n4){
    f32x4 v = *(const f32x4*)(in + (size_t)i*4);
    ushort4 o; o.x=f2bf(v.x); o.y=f2bf(v.y); o.z=f2bf(v.z); o.w=f2bf(v.w);
    *(ushort4*)(out + (size_t)i*4) = o;
  }
}

// ---------------- xp = x @ W_ih^T + b_ih ----------------
// M=32768, N=768, K=1024. A = x fp32 (converted during staging), B = W_ih bf16 (N x K, "B^T" form).
__global__ __launch_bounds__(256,1)
void gemm_xp_k(const float* __restrict__ X, const unsigned short* __restrict__ Wb,
               const float* __restrict__ bih, float* __restrict__ XP){
  __shared__ __align__(16) unsigned short sA[128*40];  // 128 rows x 32 k, stride 40 (pad)
  __shared__ __align__(16) unsigned short sB[128*40];
  int bid = blockIdx.x;
  // XCD-aware swizzle: same m-tile's 6 n-tiles land on the same XCD (L2 reuse of A rows)
  int xcd = bid & 7, loc = bid >> 3;          // 1536 = 8 * 192, 192 = 32 m * 6 n
  int mt = xcd*32 + loc/6;
  int nt = loc % 6;
  int m0 = mt*128, n0 = nt*128;
  int tid = threadIdx.x;
  int lane = tid & 63, wave = tid >> 6;
  int wm = wave >> 1, wn = wave & 1;
  int rA = lane & 15, kg = lane >> 4;
  f32x4 acc[4][4] = {};
  for (int k0 = 0; k0 < 1024; k0 += 32){
    __syncthreads();
    #pragma unroll
    for (int q = 0; q < 4; q++){           // A: 128x32 fp32 -> bf16, 4 float4 per thread
      int idx = tid + q*256;
      int r = idx >> 3, c4 = idx & 7;
      f32x4 v = *(const f32x4*)(X + (size_t)(m0+r)*1024 + k0 + c4*4);
      ushort4 o; o.x=f2bf(v.x); o.y=f2bf(v.y); o.z=f2bf(v.z); o.w=f2bf(v.w);
      *(ushort4*)&sA[r*40 + c4*4] = o;
    }
    #pragma unroll
    for (int q = 0; q < 2; q++){           // B: 128x32 bf16, 1 uint4 (8 bf16) x2 per thread
      int idx = tid + q*256;
      int n = idx >> 2, c8 = idx & 3;
      uint4 v = *(const uint4*)(Wb + (size_t)(n0+n)*1024 + k0 + c8*8);
      *(uint4*)&sB[n*40 + c8*8] = v;
    }
    __syncthreads();
    short8 af[4], bf[4];
    #pragma unroll
    for (int i=0;i<4;i++) af[i] = *(const short8*)&sA[(wm*64 + 16*i + rA)*40 + kg*8];
    #pragma unroll
    for (int j=0;j<4;j++) bf[j] = *(const short8*)&sB[(wn*64 + 16*j + rA)*40 + kg*8];
    #pragma unroll
    for (int i=0;i<4;i++)
      #pragma unroll
      for (int j=0;j<4;j++)
        acc[i][j] = __builtin_amdgcn_mfma_f32_16x16x32_bf16(af[i], bf[j], acc[i][j], 0, 0, 0);
  }
  // C/D layout (m89-verified): col = lane&15, row = (lane>>4)*4 + reg
  #pragma unroll
  for (int i=0;i<4;i++){
    int rb = m0 + wm*64 + 16*i + kg*4;
    #pragma unroll
    for (int j=0;j<4;j++){
      int cc = n0 + wn*64 + 16*j + rA;
      float bv = bih[cc];
      #pragma unroll
      for (int rg=0;rg<4;rg++)
        XP[(size_t)(rb+rg)*768 + cc] = acc[i][j][rg] + bv;
    }
  }
}

// ---------------- GRU recurrence ----------------
// 16 chains (batch) x 8 WGs each. WG (b,m) owns hidden units [32m, 32m+32):
// W_hh rows {u, 256+u, 512+u} held in registers (32 fp32/thread, 768 threads = 96KB).
// Per-step all-to-all of h via IC with device-scope atomics + per-WG step flags.
__global__ __launch_bounds__(768,1)
void gru_k(const float* __restrict__ xp, const float* __restrict__ Whh,
           const float* __restrict__ bhh, float* h_buf, int* flags,
           unsigned short* __restrict__ hs){
  int b = blockIdx.x >> 3, m = blockIdx.x & 7;
  int tid = threadIdx.x;
  int sub = tid & 7, row = tid >> 3;          // row in [0,96): g = row>>5, u = row&31
  int g = row >> 5, u = row & 31;
  int gr = g*256 + m*32 + u;                  // global row in W_hh / gate index in xp
  __shared__ __align__(16) float h_lds[256];
  __shared__ float hp_lds[96];
  __shared__ float xp_lds[2][96];
  // thread covers k = 32*jj + 4*sub + i  (jj<8, i<4) -> conflict-free LDS float4 reads
  float4 w[8];
  #pragma unroll
  for (int jj=0;jj<8;jj++)
    w[jj] = *(const float4*)(Whh + (size_t)gr*256 + 32*jj + 4*sub);
  float bh = bhh[gr];
  for (int i = tid; i < 256; i += 768) h_lds[i] = 0.f;   // h0 = 0
  int pr = (tid>>5)*256 + m*32 + (tid&31);               // xp gate row for prefetch lanes
  if (tid < 96) xp_lds[0][tid] = xp[(size_t)b*768 + pr]; // t = 0
  __syncthreads();
  for (int t = 0; t < NSTEP; t++){
    float xpn = 0.f;
    if (tid < 96 && t+1 < NSTEP)
      xpn = xp[(size_t)((t+1)*16 + b)*768 + pr];         // prefetch next step's xp
    float acc = 0.f;
    #pragma unroll
    for (int jj=0;jj<8;jj++){
      float4 h4 = *(const float4*)&h_lds[32*jj + 4*sub];
      acc = fmaf(w[jj].x, h4.x, acc);
      acc = fmaf(w[jj].y, h4.y, acc);
      acc = fmaf(w[jj].z, h4.z, acc);
      acc = fmaf(w[jj].w, h4.w, acc);
    }
    acc += __shfl_xor(acc, 1, 64);   // reduce over sub (lane-adjacent)
    acc += __shfl_xor(acc, 2, 64);
    acc += __shfl_xor(acc, 4, 64);
    if (sub == 0) hp_lds[row] = acc + bh;
    __syncthreads();
    if (tid < 32){
      float hrr = hp_lds[tid], hz = hp_lds[32+tid], hn = hp_lds[64+tid];
      float xr = xp_lds[t&1][tid], xz = xp_lds[t&1][32+tid], xn = xp_lds[t&1][64+tid];
      float sr; { float xx = xr+hrr; float e = __expf(-fabsf(xx)); float s0 = 1.f/(1.f+e); sr = xx>=0.f ? s0 : 1.f-s0; }
      float sz; { float xx = xz+hz;  float e = __expf(-fabsf(xx)); float s0 = 1.f/(1.f+e); sz = xx>=0.f ? s0 : 1.f-s0; }
      float a = xn + sr*hn;                        // n = tanh(xn + r*hn), stable form
      float ea = __expf(-2.f*fabsf(a));
      float th = (1.f-ea)/(1.f+ea);
      th = a>=0.f ? th : -th;
      float hold = h_lds[m*32 + tid];
      float hnew = (1.f-sz)*th + sz*hold;
      hs[(size_t)(t*16+b)*256 + m*32 + tid] = f2bf(hnew);
      __hip_atomic_store(h_buf + (size_t)(((t+1)&1)*16 + b)*256 + m*32 + tid, hnew,
                         __ATOMIC_RELAXED, __HIP_MEMORY_SCOPE_AGENT);
    }
    if (tid == 0)   // same wave as the h stores -> release waits their vmcnt
      __hip_atomic_store(flags + b*8 + m, t+1, __ATOMIC_RELEASE, __HIP_MEMORY_SCOPE_AGENT);
    if (tid < 96 && t+1 < NSTEP) xp_lds[(t+1)&1][tid] = xpn;
    if (t+1 < NSTEP){
      if (tid < 8){
        while (__hip_atomic_load(flags + b*8 + tid, __ATOMIC_ACQUIRE, __HIP_MEMORY_SCOPE_AGENT) < t+1){}
      }
      __syncthreads();
      if (tid < 256)
        h_lds[tid] = __hip_atomic_load(h_buf + (size_t)(((t+1)&1)*16 + b)*256 + tid,
                                       __ATOMIC_RELAXED, __HIP_MEMORY_SCOPE_AGENT);
      __syncthreads();
    }
  }
}

// ---------------- head: relu(h) @ W_out^T + b_out, softmax, outputs, task bins ----------------
__global__ __launch_bounds__(256,1)
void head_k(const unsigned short* __restrict__ hs, const float* __restrict__ Wout,
            const float* __restrict__ bout, const int* __restrict__ task,
            float* __restrict__ out, float* __restrict__ sums, float* __restrict__ counts){
  __shared__ float sW[1024];
  __shared__ float sbin[8], scnt[8];
  int tid = threadIdx.x;
  for (int i = tid; i < 1024; i += 256) sW[i] = Wout[i];
  if (tid < 8){ sbin[tid] = 0.f; scnt[tid] = 0.f; }
  __syncthreads();
  int rowi = blockIdx.x*256 + tid;   // 32768 rows total
  const uint* hp = (const uint*)(hs + (size_t)rowi*256);
  float l0 = bout[0], l1 = bout[1], l2 = bout[2], l3 = bout[3];
  #pragma unroll 4
  for (int c = 0; c < 32; c++){
    uint4 v = *(const uint4*)(hp + c*4);
    uint vv0 = v.x, vv1 = v.y, vv2 = v.z, vv3 = v.w;
    uint arr[4] = {vv0, vv1, vv2, vv3};
    #pragma unroll
    for (int q = 0; q < 4; q++){
      float h0 = __builtin_bit_cast(float, arr[q] << 16);
      float h1 = __builtin_bit_cast(float, arr[q] & 0xFFFF0000u);
      h0 = fmaxf(h0, 0.f); h1 = fmaxf(h1, 0.f);
      int k = c*8 + q*2;
      l0 = fmaf(h0, sW[k],     l0); l0 = fmaf(h1, sW[k+1],   l0);
      l1 = fmaf(h0, sW[256+k], l1); l1 = fmaf(h1, sW[257+k], l1);
      l2 = fmaf(h0, sW[512+k], l2); l2 = fmaf(h1, sW[513+k], l2);
      l3 = fmaf(h0, sW[768+k], l3); l3 = fmaf(h1, sW[769+k], l3);
    }
  }
  float mx = fmaxf(fmaxf(l0,l1), fmaxf(l2,l3));
  float e0 = __expf(l0-mx), e1 = __expf(l1-mx), e2 = __expf(l2-mx), e3 = __expf(l3-mx);
  float inv = 1.f/(e0+e1+e2+e3);
  float p0 = e0*inv, p1 = e1*inv, p2 = e2*inv, p3 = e3*inv;
  size_t o = (size_t)rowi*4;
  out[o+0]=p0; out[o+1]=p1; out[o+2]=p2; out[o+3]=p3;                    // raw_router_output
  out[131072+o+0]=p0; out[131072+o+1]=p1; out[131072+o+2]=p2; out[131072+o+3]=p3;  // router_output
  out[262144+o+0]=0.f; out[262144+o+1]=1.f; out[262144+o+2]=2.f; out[262144+o+3]=3.f; // indices
  float loss = 256.f*p0 + 512.f*p1 + 1024.f*p2 + 2048.f*p3;
  int tk = task[rowi] & 7;
  atomicAdd(&sbin[tk], loss);
  atomicAdd(&scnt[tk], 1.f);
  __syncthreads();
  if (tid < 8){
    atomicAdd(&sums[tid], sbin[tid]);
    atomicAdd(&counts[tid], scnt[tid]);
  }
}

__global__ void fin_k(const float* __restrict__ sums, const float* __restrict__ counts,
                      float* __restrict__ o3){
  int i = threadIdx.x;
  if (i < 8){ float c = counts[i]; o3[i] = c > 0.f ? sums[i]/c : 0.f; }
}

extern "C" void kernel_launch(void* const* d_in, const int* in_sizes, int n_in,
                              void* d_out, int out_size, void* d_ws, size_t ws_size,
                              hipStream_t stream){
  const float* x    = (const float*)d_in[0];
  const int*   task = (const int*)d_in[1];
  const float* Wih  = (const float*)d_in[2];
  const float* Whh  = (const float*)d_in[3];
  const float* bih  = (const float*)d_in[4];
  const float* bhh  = (const float*)d_in[5];
  const float* Wout = (const float*)d_in[6];
  const float* bout = (const float*)d_in[7];
  float* out = (float*)d_out;
  char* ws = (char*)d_ws;
  // workspace layout (~113.5 MiB total)
  unsigned short* wih_bf = (unsigned short*)ws;              // 1,572,864 B
  float* xp    = (float*)(ws + 1572864);                     // 100,663,296 B
  unsigned short* hs = (unsigned short*)(ws + 102236160);    // 16,777,216 B
  float* h_buf = (float*)(ws + 119013376);                   // 32,768 B
  int* flags   = (int*)(ws + 119046144);                     // 1,024 B (pad)
  float* sums  = (float*)(ws + 119047168);                   // 32 B
  float* counts= (float*)(ws + 119047200);                   // 32 B

  hipMemsetAsync(flags, 0, 1024 + 64, stream);               // flags + sums + counts

  cvt_bf16_k<<<768, 256, 0, stream>>>(Wih, wih_bf, 196608);
  gemm_xp_k<<<1536, 256, 0, stream>>>(x, wih_bf, bih, xp);
  gru_k<<<128, 768, 0, stream>>>(xp, Whh, bhh, h_buf, flags, hs);
  head_k<<<128, 256, 0, stream>>>(hs, Wout, bout, task, out, sums, counts);
  fin_k<<<1, 64, 0, stream>>>(sums, counts, out + 393216);
}

// Round 2
// 2595.339 us; speedup vs baseline: 3.3801x; 3.3801x over previous
//
#include <hip/hip_runtime.h>

#define NSTEP 2048

typedef __attribute__((ext_vector_type(8))) short short8;
typedef __attribute__((ext_vector_type(4))) float f32x4;

static __device__ __forceinline__ unsigned short f2bf(float f){
  unsigned u = __builtin_bit_cast(unsigned, f);
  u += 0x7FFFu + ((u >> 16) & 1u);   // RNE
  return (unsigned short)(u >> 16);
}

static __device__ __forceinline__ short8 pack8(f32x4 lo, f32x4 hi){
  short8 r;
  r[0]=(short)f2bf(lo.x); r[1]=(short)f2bf(lo.y); r[2]=(short)f2bf(lo.z); r[3]=(short)f2bf(lo.w);
  r[4]=(short)f2bf(hi.x); r[5]=(short)f2bf(hi.y); r[6]=(short)f2bf(hi.z); r[7]=(short)f2bf(hi.w);
  return r;
}

// ---------------- fp32 -> bf16 (for W_ih) ----------------
__global__ __launch_bounds__(256,1)
void cvt_bf16_k(const float* __restrict__ in, unsigned short* __restrict__ out, int n4){
  int i = blockIdx.x*256 + threadIdx.x;
  if (i < n4){
    f32x4 v = *(const f32x4*)(in + (size_t)i*4);
    ushort4 o; o.x=f2bf(v.x); o.y=f2bf(v.y); o.z=f2bf(v.z); o.w=f2bf(v.w);
    *(ushort4*)(out + (size_t)i*4) = o;
  }
}

// ---------------- xp = x @ W_ih^T + b_ih ----------------
// M=32768, N=768, K=1024. A = x fp32 (converted during staging), B = W_ih bf16 (N x K).
__global__ __launch_bounds__(256,1)
void gemm_xp_k(const float* __restrict__ X, const unsigned short* __restrict__ Wb,
               const float* __restrict__ bih, float* __restrict__ XP){
  __shared__ __align__(16) unsigned short sA[128*40];
  __shared__ __align__(16) unsigned short sB[128*40];
  int bid = blockIdx.x;
  int xcd = bid & 7, loc = bid >> 3;          // 1536 = 8 * 192
  int mt = xcd*32 + loc/6;
  int nt = loc % 6;
  int m0 = mt*128, n0 = nt*128;
  int tid = threadIdx.x;
  int lane = tid & 63, wave = tid >> 6;
  int wm = wave >> 1, wn = wave & 1;
  int rA = lane & 15, kg = lane >> 4;
  f32x4 acc[4][4] = {};
  for (int k0 = 0; k0 < 1024; k0 += 32){
    __syncthreads();
    #pragma unroll
    for (int q = 0; q < 4; q++){
      int idx = tid + q*256;
      int r = idx >> 3, c4 = idx & 7;
      f32x4 v = *(const f32x4*)(X + (size_t)(m0+r)*1024 + k0 + c4*4);
      ushort4 o; o.x=f2bf(v.x); o.y=f2bf(v.y); o.z=f2bf(v.z); o.w=f2bf(v.w);
      *(ushort4*)&sA[r*40 + c4*4] = o;
    }
    #pragma unroll
    for (int q = 0; q < 2; q++){
      int idx = tid + q*256;
      int n = idx >> 2, c8 = idx & 3;
      uint4 v = *(const uint4*)(Wb + (size_t)(n0+n)*1024 + k0 + c8*8);
      *(uint4*)&sB[n*40 + c8*8] = v;
    }
    __syncthreads();
    short8 af[4], bf[4];
    #pragma unroll
    for (int i=0;i<4;i++) af[i] = *(const short8*)&sA[(wm*64 + 16*i + rA)*40 + kg*8];
    #pragma unroll
    for (int j=0;j<4;j++) bf[j] = *(const short8*)&sB[(wn*64 + 16*j + rA)*40 + kg*8];
    #pragma unroll
    for (int i=0;i<4;i++)
      #pragma unroll
      for (int j=0;j<4;j++)
        acc[i][j] = __builtin_amdgcn_mfma_f32_16x16x32_bf16(af[i], bf[j], acc[i][j], 0, 0, 0);
  }
  #pragma unroll
  for (int i=0;i<4;i++){
    int rb = m0 + wm*64 + 16*i + kg*4;
    #pragma unroll
    for (int j=0;j<4;j++){
      int cc = n0 + wn*64 + 16*j + rA;
      float bv = bih[cc];
      #pragma unroll
      for (int rg=0;rg<4;rg++)
        XP[(size_t)(rb+rg)*768 + cc] = acc[i][j][rg] + bv;
    }
  }
}

// ---------------- GRU recurrence: one WG per chain, zero cross-WG sync ----------------
// 16 WGs x 512 threads (8 waves). W_hh held in registers as MFMA B-fragments:
// wave w owns gate-rows [96w, 96w+96) -> 6 n-tiles x 8 k-tiles = 48 short8 frags (192 VGPR).
// h (bf16) broadcast from LDS as the A operand (M=1: all 16 lanes of a quarter read the
// same 16B -> LDS broadcast, conflict-free; redundant M-rows compute duplicates, unused).
// Gates on threads 0-255 (fp32 state in LDS); xp double-buffer streamed by threads 256-511.
__global__ __launch_bounds__(512,2)
void gru_k(const float* __restrict__ xp, const float* __restrict__ Whh,
           const float* __restrict__ bhh, unsigned short* __restrict__ hs){
  int b = blockIdx.x;
  int tid = threadIdx.x;
  int wave = tid >> 6, lane = tid & 63;
  int rA = lane & 15, kg = lane >> 4;
  __shared__ __align__(16) unsigned short h_bf[256];
  __shared__ float h_f32[256];
  __shared__ float hp_lds[768];
  __shared__ float xp_lds[2][768];

  // ---- preload W_hh fragments (startup only) ----
  short8 bw[6][8];
  const float* wbase = Whh + (size_t)(96*wave + rA)*256 + kg*8;
  #pragma unroll
  for (int nt=0; nt<6; nt++){
    #pragma unroll
    for (int kk=0; kk<8; kk++){
      const float* p = wbase + nt*16*256 + kk*32;
      f32x4 lo = *(const f32x4*)p;
      f32x4 hi = *(const f32x4*)(p+4);
      bw[nt][kk] = pack8(lo, hi);
    }
  }
  float br=0.f, bz=0.f, bn=0.f;
  if (tid < 256){
    br = bhh[tid]; bz = bhh[256+tid]; bn = bhh[512+tid];
    h_bf[tid] = 0; h_f32[tid] = 0.f;
  } else {
    int c = tid - 256;
    const float* q = xp + (size_t)b*768 + c;   // xp row for t=0
    xp_lds[0][c]     = q[0];
    xp_lds[0][256+c] = q[256];
    xp_lds[0][512+c] = q[512];
  }
  __syncthreads();

  for (int t = 0; t < NSTEP; t++){
    // (1) issue next-step xp prefetch (hidden under MFMA)
    float p0=0.f, p1=0.f, p2=0.f;
    if (tid >= 256 && t+1 < NSTEP){
      const float* q = xp + (size_t)((t+1)*16 + b)*768 + (tid - 256);
      p0 = q[0]; p1 = q[256]; p2 = q[512];
    }
    // (2) hp = h @ W_hh^T  (M=1 MFMA, A broadcast from LDS)
    f32x4 acc[6] = {};
    #pragma unroll
    for (int kk=0; kk<8; kk++){
      short8 a = *(const short8*)&h_bf[kk*32 + kg*8];   // quarter-uniform broadcast
      #pragma unroll
      for (int nt=0; nt<6; nt++)
        acc[nt] = __builtin_amdgcn_mfma_f32_16x16x32_bf16(a, bw[nt][kk], acc[nt], 0, 0, 0);
    }
    // (3) D row m=0 lives in lanes kg==0, reg 0
    if (kg == 0){
      #pragma unroll
      for (int nt=0; nt<6; nt++)
        hp_lds[96*wave + 16*nt + rA] = acc[nt][0];
    }
    // (4) land xp prefetch in the other buffer
    if (tid >= 256 && t+1 < NSTEP){
      int c = tid - 256, nb = (t+1)&1;
      xp_lds[nb][c] = p0; xp_lds[nb][256+c] = p1; xp_lds[nb][512+c] = p2;
    }
    __syncthreads();
    // (5) gates: 256 threads, one hidden unit each; fp32 carried state
    if (tid < 256){
      int u = tid, cb = t & 1;
      float hr = hp_lds[u]       + br;
      float hz = hp_lds[256 + u] + bz;
      float hn = hp_lds[512 + u] + bn;
      float xr = xp_lds[cb][u], xz = xp_lds[cb][256+u], xn = xp_lds[cb][512+u];
      float sr; { float xx = xr+hr; float e = __expf(-fabsf(xx)); float s0 = 1.f/(1.f+e); sr = xx>=0.f ? s0 : 1.f-s0; }
      float sz; { float xx = xz+hz; float e = __expf(-fabsf(xx)); float s0 = 1.f/(1.f+e); sz = xx>=0.f ? s0 : 1.f-s0; }
      float a  = xn + sr*hn;
      float ea = __expf(-2.f*fabsf(a));
      float th = (1.f-ea)/(1.f+ea);
      th = a>=0.f ? th : -th;
      float hold = h_f32[u];
      float hnew = (1.f-sz)*th + sz*hold;
      unsigned short hb = f2bf(hnew);
      h_f32[u] = hnew;
      h_bf[u]  = hb;
      hs[((size_t)t*16 + b)*256 + u] = hb;
    }
    __syncthreads();
  }
}

// ---------------- head: relu(h) @ W_out^T + b_out, softmax, outputs, task bins ----------------
__global__ __launch_bounds__(256,1)
void head_k(const unsigned short* __restrict__ hs, const float* __restrict__ Wout,
            const float* __restrict__ bout, const int* __restrict__ task,
            float* __restrict__ out, float* __restrict__ sums, float* __restrict__ counts){
  __shared__ float sW[1024];
  __shared__ float sbin[8], scnt[8];
  int tid = threadIdx.x;
  for (int i = tid; i < 1024; i += 256) sW[i] = Wout[i];
  if (tid < 8){ sbin[tid] = 0.f; scnt[tid] = 0.f; }
  __syncthreads();
  int rowi = blockIdx.x*256 + tid;   // 32768 rows total
  const uint* hp = (const uint*)(hs + (size_t)rowi*256);
  float l0 = bout[0], l1 = bout[1], l2 = bout[2], l3 = bout[3];
  #pragma unroll 4
  for (int c = 0; c < 32; c++){
    uint4 v = *(const uint4*)(hp + c*4);
    uint arr[4] = {v.x, v.y, v.z, v.w};
    #pragma unroll
    for (int q = 0; q < 4; q++){
      float h0 = __builtin_bit_cast(float, arr[q] << 16);
      float h1 = __builtin_bit_cast(float, arr[q] & 0xFFFF0000u);
      h0 = fmaxf(h0, 0.f); h1 = fmaxf(h1, 0.f);
      int k = c*8 + q*2;
      l0 = fmaf(h0, sW[k],     l0); l0 = fmaf(h1, sW[k+1],   l0);
      l1 = fmaf(h0, sW[256+k], l1); l1 = fmaf(h1, sW[257+k], l1);
      l2 = fmaf(h0, sW[512+k], l2); l2 = fmaf(h1, sW[513+k], l2);
      l3 = fmaf(h0, sW[768+k], l3); l3 = fmaf(h1, sW[769+k], l3);
    }
  }
  float mx = fmaxf(fmaxf(l0,l1), fmaxf(l2,l3));
  float e0 = __expf(l0-mx), e1 = __expf(l1-mx), e2 = __expf(l2-mx), e3 = __expf(l3-mx);
  float inv = 1.f/(e0+e1+e2+e3);
  float p0 = e0*inv, p1 = e1*inv, p2 = e2*inv, p3 = e3*inv;
  size_t o = (size_t)rowi*4;
  out[o+0]=p0; out[o+1]=p1; out[o+2]=p2; out[o+3]=p3;
  out[131072+o+0]=p0; out[131072+o+1]=p1; out[131072+o+2]=p2; out[131072+o+3]=p3;
  out[262144+o+0]=0.f; out[262144+o+1]=1.f; out[262144+o+2]=2.f; out[262144+o+3]=3.f;
  float loss = 256.f*p0 + 512.f*p1 + 1024.f*p2 + 2048.f*p3;
  int tk = task[rowi] & 7;
  atomicAdd(&sbin[tk], loss);
  atomicAdd(&scnt[tk], 1.f);
  __syncthreads();
  if (tid < 8){
    atomicAdd(&sums[tid], sbin[tid]);
    atomicAdd(&counts[tid], scnt[tid]);
  }
}

__global__ void fin_k(const float* __restrict__ sums, const float* __restrict__ counts,
                      float* __restrict__ o3){
  int i = threadIdx.x;
  if (i < 8){ float c = counts[i]; o3[i] = c > 0.f ? sums[i]/c : 0.f; }
}

extern "C" void kernel_launch(void* const* d_in, const int* in_sizes, int n_in,
                              void* d_out, int out_size, void* d_ws, size_t ws_size,
                              hipStream_t stream){
  const float* x    = (const float*)d_in[0];
  const int*   task = (const int*)d_in[1];
  const float* Wih  = (const float*)d_in[2];
  const float* Whh  = (const float*)d_in[3];
  const float* bih  = (const float*)d_in[4];
  const float* bhh  = (const float*)d_in[5];
  const float* Wout = (const float*)d_in[6];
  const float* bout = (const float*)d_in[7];
  float* out = (float*)d_out;
  char* ws = (char*)d_ws;
  unsigned short* wih_bf = (unsigned short*)ws;              // 1,572,864 B
  float* xp    = (float*)(ws + 1572864);                     // 100,663,296 B
  unsigned short* hs = (unsigned short*)(ws + 102236160);    // 16,777,216 B
  float* sums  = (float*)(ws + 119013376);                   // 32 B
  float* counts= (float*)(ws + 119013408);                   // 32 B

  hipMemsetAsync(sums, 0, 64, stream);

  cvt_bf16_k<<<768, 256, 0, stream>>>(Wih, wih_bf, 196608);
  gemm_xp_k<<<1536, 256, 0, stream>>>(x, wih_bf, bih, xp);
  gru_k<<<16, 512, 0, stream>>>(xp, Whh, bhh, hs);
  head_k<<<128, 256, 0, stream>>>(hs, Wout, bout, task, out, sums, counts);
  fin_k<<<1, 64, 0, stream>>>(sums, counts, out + 393216);
}